// Round 2
// baseline (535.151 us; speedup 1.0000x reference)
//
#include <hip/hip_runtime.h>

// Problem constants (from reference setup_inputs)
constexpr int N = 50000;       // nodes
constexpr int D = 64;          // feature dim
constexpr int E = 1600000;     // edges

// ---------------------------------------------------------------------------
// K1: in-degree via int atomics over dst
__global__ void k_deg(const int* __restrict__ dst, unsigned* __restrict__ deg) {
    int e = blockIdx.x * blockDim.x + threadIdx.x;
    if (e < E) atomicAdd(&deg[dst[e]], 1u);
}

// K2: norm[i] = deg>0 ? rsqrt(deg) : 0
__global__ void k_norm(const unsigned* __restrict__ deg, float* __restrict__ norm) {
    int i = blockIdx.x * blockDim.x + threadIdx.x;
    if (i < N) {
        unsigned d = deg[i];
        norm[i] = d ? rsqrtf((float)d) : 0.0f;
    }
}

// K3: h2[row][d] = (sum_k x[row][k] * W[k][d]) * norm[row]   (fp32)
// 256 threads = 4 rows/block; W staged in LDS via float4.
__global__ void k_gemm(const float* __restrict__ x,
                       const float* __restrict__ W,
                       const float* __restrict__ norm,
                       float* __restrict__ h2) {
    __shared__ float Wl[64 * 64];
    __shared__ float xs[4][64];
    int tid = threadIdx.x;
    const float4* W4 = (const float4*)W;
    float4* Wl4 = (float4*)Wl;
    for (int i = tid; i < 1024; i += 256) Wl4[i] = W4[i];   // 64*64 floats
    int r = tid >> 6, d = tid & 63;
    int row = blockIdx.x * 4 + r;
    xs[r][d] = x[row * 64 + d];
    __syncthreads();
    float a = 0.0f;
#pragma unroll
    for (int k = 0; k < 64; ++k) a = fmaf(xs[r][k], Wl[k * 64 + d], a);
    h2[row * 64 + d] = a * norm[row];
}

// K4: edge scatter — 4 waves/block, one edge per wave; lane d adds
// h2[src][d] into acc[dst][d] with the HW f32 atomic.
__global__ void k_scatter(const int* __restrict__ src, const int* __restrict__ dst,
                          const float* __restrict__ h2, float* __restrict__ acc) {
    int e = blockIdx.x * 4 + (threadIdx.x >> 6);
    int d = threadIdx.x & 63;
    int s = src[e];
    int t = dst[e];
    float v = h2[s * 64 + d];
    unsafeAtomicAdd(&acc[t * 64 + d], v);   // global_atomic_add_f32
}

// K5: out = softplus(acc * norm[row] + bias[d])  (fp32 out)
__global__ void k_final(const float* __restrict__ acc, const float* __restrict__ norm,
                        const float* __restrict__ bias,
                        float* __restrict__ out) {
    int idx = blockIdx.x * blockDim.x + threadIdx.x;   // over N*D
    int row = idx >> 6;
    int d = idx & 63;
    float v = acc[idx] * norm[row] + bias[d];
    // numerically stable softplus: max(v,0) + log1p(exp(-|v|))
    float sp = fmaxf(v, 0.0f) + log1pf(expf(-fabsf(v)));
    out[idx] = sp;
}

extern "C" void kernel_launch(void* const* d_in, const int* in_sizes, int n_in,
                              void* d_out, int out_size, void* d_ws, size_t ws_size,
                              hipStream_t stream) {
    // inputs: t(f32,1), x(f32,N*D), weight(f32,D*D), bias(f32,D), src(i32,E), dst(i32,E)
    const float* x    = (const float*)d_in[1];
    const float* W    = (const float*)d_in[2];
    const float* bias = (const float*)d_in[3];
    const int* src = (const int*)d_in[4];
    const int* dst = (const int*)d_in[5];
    float* out = (float*)d_out;

    // workspace layout (harness poisons d_ws with 0xAA before every launch)
    char* ws = (char*)d_ws;
    float*    acc  = (float*)(ws);                          // N*D f32 = 12.8 MB
    float*    h2   = (float*)(ws + (size_t)N * D * 4);      // N*D f32 = 12.8 MB
    unsigned* deg  = (unsigned*)(ws + (size_t)2 * N * D * 4);           // N u32
    float*    norm = (float*)(ws + (size_t)2 * N * D * 4 + (size_t)N * 4); // N f32

    hipMemsetAsync(acc, 0, (size_t)N * D * sizeof(float), stream);
    hipMemsetAsync(deg, 0, (size_t)N * sizeof(unsigned), stream);

    k_deg<<<E / 256, 256, 0, stream>>>(dst, deg);
    k_norm<<<(N + 255) / 256, 256, 0, stream>>>(deg, norm);
    k_gemm<<<N / 4, 256, 0, stream>>>(x, W, norm, h2);
    k_scatter<<<E / 4, 256, 0, stream>>>(src, dst, h2, acc);
    k_final<<<(N * D) / 256, 256, 0, stream>>>(acc, norm, bias, out);
}

// Round 3
// 401.485 us; speedup vs baseline: 1.3329x; 1.3329x over previous
//
#include <hip/hip_runtime.h>

constexpr int N = 50000;       // nodes
constexpr int D = 64;          // feature dim
constexpr int E = 1600000;     // edges
constexpr int NB = (N + 255) / 256;   // scan blocks = 196

// ---------------------------------------------------------------------------
// K1: in-degree via int atomics over dst
__global__ void k_deg(const int* __restrict__ dst, int* __restrict__ deg) {
    int e = blockIdx.x * blockDim.x + threadIdx.x;
    if (e < E) atomicAdd(&deg[dst[e]], 1);
}

// K2: norm[i] = deg>0 ? rsqrt(deg) : 0
__global__ void k_norm(const int* __restrict__ deg, float* __restrict__ norm) {
    int i = blockIdx.x * blockDim.x + threadIdx.x;
    if (i < N) {
        int d = deg[i];
        norm[i] = d ? rsqrtf((float)d) : 0.0f;
    }
}

// K3a: per-block sums of deg
__global__ void k_blocksum(const int* __restrict__ deg, int* __restrict__ partial) {
    __shared__ int sm[256];
    int t = threadIdx.x;
    int i = blockIdx.x * 256 + t;
    sm[t] = (i < N) ? deg[i] : 0;
    __syncthreads();
    for (int s = 128; s > 0; s >>= 1) {
        if (t < s) sm[t] += sm[t + s];
        __syncthreads();
    }
    if (t == 0) partial[blockIdx.x] = sm[0];
}

// K3b: exclusive scan of the NB partials (single block, NB<=256)
__global__ void k_scanpartial(int* __restrict__ partial) {
    __shared__ int sm[256];
    int t = threadIdx.x;
    sm[t] = (t < NB) ? partial[t] : 0;
    __syncthreads();
    for (int off = 1; off < 256; off <<= 1) {
        int v = (t >= off) ? sm[t - off] : 0;
        __syncthreads();
        sm[t] += v;
        __syncthreads();
    }
    if (t < NB) partial[t] = (t == 0) ? 0 : sm[t - 1];   // exclusive
}

// K3c: per-block exclusive scan + partial offset -> rowptr, cursor
__global__ void k_rowptr(const int* __restrict__ deg, const int* __restrict__ partial,
                         int* __restrict__ rowptr, int* __restrict__ cursor) {
    __shared__ int sm[256];
    int t = threadIdx.x;
    int i = blockIdx.x * 256 + t;
    sm[t] = (i < N) ? deg[i] : 0;
    __syncthreads();
    for (int off = 1; off < 256; off <<= 1) {
        int v = (t >= off) ? sm[t - off] : 0;
        __syncthreads();
        sm[t] += v;
        __syncthreads();
    }
    int excl = ((t == 0) ? 0 : sm[t - 1]) + partial[blockIdx.x];
    if (i < N) { rowptr[i] = excl; cursor[i] = excl; }
    if (i == 0) rowptr[N] = E;
}

// K4: fill CSR column list (src of each incoming edge, grouped by dst)
__global__ void k_fill(const int* __restrict__ src, const int* __restrict__ dst,
                       int* __restrict__ cursor, int* __restrict__ csr_src) {
    int e = blockIdx.x * blockDim.x + threadIdx.x;
    if (e < E) {
        int slot = atomicAdd(&cursor[dst[e]], 1);
        csr_src[slot] = src[e];
    }
}

// K5: h2[row][d] = (sum_k x[row][k] * W[k][d]) * norm[row]   (fp32)
__global__ void k_gemm(const float* __restrict__ x,
                       const float* __restrict__ W,
                       const float* __restrict__ norm,
                       float* __restrict__ h2) {
    __shared__ float Wl[64 * 64];
    __shared__ float xs[4][64];
    int tid = threadIdx.x;
    const float4* W4 = (const float4*)W;
    float4* Wl4 = (float4*)Wl;
    for (int i = tid; i < 1024; i += 256) Wl4[i] = W4[i];
    int r = tid >> 6, d = tid & 63;
    int row = blockIdx.x * 4 + r;
    xs[r][d] = x[row * 64 + d];
    __syncthreads();
    float a = 0.0f;
#pragma unroll
    for (int k = 0; k < 64; ++k) a = fmaf(xs[r][k], Wl[k * 64 + d], a);
    h2[row * 64 + d] = a * norm[row];
}

// K6: fused aggregate + dst-norm + bias + softplus.
// One wave per node: lane d accumulates sum over incoming edges of h2[src][d]
// in a register; single coalesced 256B row store at the end. No float atomics.
__global__ void k_aggregate(const int* __restrict__ rowptr, const int* __restrict__ csr_src,
                            const float* __restrict__ h2, const float* __restrict__ norm,
                            const float* __restrict__ bias, float* __restrict__ out) {
    int node = blockIdx.x * 4 + (threadIdx.x >> 6);
    int lane = threadIdx.x & 63;
    if (node >= N) return;
    int beg = rowptr[node];
    int end = rowptr[node + 1];
    float a = 0.0f;
    int j = beg;
    // unroll x2 for memory-level parallelism
    for (; j + 1 < end; j += 2) {
        int s0 = csr_src[j];
        int s1 = csr_src[j + 1];
        float v0 = h2[s0 * 64 + lane];
        float v1 = h2[s1 * 64 + lane];
        a += v0;
        a += v1;
    }
    if (j < end) a += h2[csr_src[j] * 64 + lane];
    float v = a * norm[node] + bias[lane];
    out[node * 64 + lane] = fmaxf(v, 0.0f) + log1pf(expf(-fabsf(v)));
}

extern "C" void kernel_launch(void* const* d_in, const int* in_sizes, int n_in,
                              void* d_out, int out_size, void* d_ws, size_t ws_size,
                              hipStream_t stream) {
    // inputs: t(f32,1), x(f32,N*D), weight(f32,D*D), bias(f32,D), src(i32,E), dst(i32,E)
    const float* x    = (const float*)d_in[1];
    const float* W    = (const float*)d_in[2];
    const float* bias = (const float*)d_in[3];
    const int* src = (const int*)d_in[4];
    const int* dst = (const int*)d_in[5];
    float* out = (float*)d_out;

    // workspace layout (~19.8 MB; harness poisons with 0xAA every call)
    char* ws = (char*)d_ws;
    float* h2      = (float*)(ws);                                   // N*D f32
    int*   csr_src = (int*)(ws + (size_t)N * D * 4);                 // E i32
    int*   deg     = (int*)(ws + (size_t)N * D * 4 + (size_t)E * 4); // N
    float* norm    = (float*)((char*)deg + (size_t)N * 4);           // N
    int*   rowptr  = (int*)((char*)norm + (size_t)N * 4);            // N+1
    int*   cursor  = (int*)((char*)rowptr + (size_t)(N + 1) * 4);    // N
    int*   partial = (int*)((char*)cursor + (size_t)N * 4);          // NB

    hipMemsetAsync(deg, 0, (size_t)N * sizeof(int), stream);

    k_deg<<<(E + 255) / 256, 256, 0, stream>>>(dst, deg);
    k_norm<<<(N + 255) / 256, 256, 0, stream>>>(deg, norm);
    k_blocksum<<<NB, 256, 0, stream>>>(deg, partial);
    k_scanpartial<<<1, 256, 0, stream>>>(partial);
    k_rowptr<<<NB, 256, 0, stream>>>(deg, partial, rowptr, cursor);
    k_fill<<<(E + 255) / 256, 256, 0, stream>>>(src, dst, cursor, csr_src);
    k_gemm<<<N / 4, 256, 0, stream>>>(x, W, norm, h2);
    k_aggregate<<<(N + 3) / 4, 256, 0, stream>>>(rowptr, csr_src, h2, norm, bias, out);
}